// Round 1
// baseline (374.808 us; speedup 1.0000x reference)
//
#include <hip/hip_runtime.h>
#include <stdint.h>

#define F8MAX 448.0f
#define QEPS 1e-12f

typedef float floatx4 __attribute__((ext_vector_type(4)));

// ---------------- pass 1: per-block amax partials ----------------
__global__ void amax_partial(const float* __restrict__ in, int n4, float* __restrict__ partial)
{
    const float4* in4 = (const float4*)in;
    int tid = blockIdx.x * blockDim.x + threadIdx.x;
    int stride = gridDim.x * blockDim.x;
    float m = 0.0f;
    for (int i = tid; i < n4; i += stride) {
        float4 v = in4[i];
        m = fmaxf(m, fmaxf(fmaxf(fabsf(v.x), fabsf(v.y)), fmaxf(fabsf(v.z), fabsf(v.w))));
    }
    #pragma unroll
    for (int off = 32; off > 0; off >>= 1)
        m = fmaxf(m, __shfl_xor(m, off, 64));
    __shared__ float sm[4];
    if ((threadIdx.x & 63) == 0) sm[threadIdx.x >> 6] = m;
    __syncthreads();
    if (threadIdx.x == 0)
        partial[blockIdx.x] = fmaxf(fmaxf(sm[0], sm[1]), fmaxf(sm[2], sm[3]));
}

// ---------------- pass 2: final reduce of both partial arrays ----------------
__global__ void final_reduce(const float* __restrict__ px, int nx,
                             const float* __restrict__ pw, int nw,
                             unsigned* __restrict__ hdr)
{
    float mx = 0.0f, mw = 0.0f;
    for (int i = threadIdx.x; i < nx; i += 256) mx = fmaxf(mx, px[i]);
    for (int i = threadIdx.x; i < nw; i += 256) mw = fmaxf(mw, pw[i]);
    #pragma unroll
    for (int off = 32; off > 0; off >>= 1) {
        mx = fmaxf(mx, __shfl_xor(mx, off, 64));
        mw = fmaxf(mw, __shfl_xor(mw, off, 64));
    }
    __shared__ float sx[4], sw[4];
    if ((threadIdx.x & 63) == 0) { sx[threadIdx.x >> 6] = mx; sw[threadIdx.x >> 6] = mw; }
    __syncthreads();
    if (threadIdx.x == 0) {
        float ax = fmaxf(fmaxf(sx[0], sx[1]), fmaxf(sx[2], sx[3]));
        float aw = fmaxf(fmaxf(sw[0], sw[1]), fmaxf(sw[2], sw[3]));
        hdr[0] = __float_as_uint(ax);
        hdr[1] = __float_as_uint(aw);
    }
}

// ---------------- pass 3: quantize fp32 -> fp8 e4m3 (RNE, exact ref semantics) ----------------
__global__ void quant_fp8(const float* __restrict__ in, uint8_t* __restrict__ out,
                          const unsigned* __restrict__ hdr, int hidx, int n)
{
    int tid = blockIdx.x * blockDim.x + threadIdx.x;
    int base = tid * 16;
    if (base >= n) return;
    float amax = __uint_as_float(hdr[hidx]);
    float scale = fmaxf(amax, QEPS) / F8MAX;   // true fp32 division (matches ref)
    const float4* in4 = (const float4*)(in + base);
    int w[4];
    #pragma unroll
    for (int i = 0; i < 4; i++) {
        float4 v = in4[i];
        float a = v.x / scale, b = v.y / scale, c = v.z / scale, d = v.w / scale;
        int word = 0;
        word = __builtin_amdgcn_cvt_pk_fp8_f32(a, b, word, false);  // bytes 0,1
        word = __builtin_amdgcn_cvt_pk_fp8_f32(c, d, word, true);   // bytes 2,3
        w[i] = word;
    }
    int4 r; r.x = w[0]; r.y = w[1]; r.z = w[2]; r.w = w[3];
    *(int4*)(out + base) = r;
}

// ---------------- pass 4: fp8 GEMM, m97 structure ----------------
// C[M,N] = (A8[M,K] . B8[N,K]^T) * s + bias[N]
__global__ __launch_bounds__(256) void gemm_fp8(
    const uint8_t* __restrict__ A8, const uint8_t* __restrict__ B8,
    float* __restrict__ C, const float* __restrict__ bias,
    const unsigned* __restrict__ hdr, int M, int N, int K, int nbn, int swz)
{
    __shared__ uint8_t lsA[128 * 64];
    __shared__ uint8_t lsB[128 * 64];

    int bid = blockIdx.x;
    int bm, bn;
    if (swz) {
        // group 8 M-panels x all N-tiles so that one XCD sees all bn of a bm (A-tile L2 reuse)
        int grp = bid / (8 * nbn);
        int within = bid - grp * (8 * nbn);
        bm = grp * 8 + (within & 7);
        bn = within >> 3;
    } else {
        bm = bid / nbn;
        bn = bid - bm * nbn;
    }

    int t = threadIdx.x;
    int wave = t >> 6;
    int lane = t & 63;
    int wr = wave >> 1, wc = wave & 1;

    // staging: each wave covers 16 rows x 64B per instr; 2 instrs per operand half
    int srow = wave * 16 + (lane >> 2);
    int scol = (lane & 3) * 16;
    const uint8_t* ga = A8 + (size_t)(bm * 128 + srow) * K + scol;
    const uint8_t* gb = B8 + (size_t)(bn * 128 + srow) * K + scol;
    uint8_t* la = &lsA[wave * 1024];
    uint8_t* lb = &lsB[wave * 1024];

    floatx4 acc[4][4];
    #pragma unroll
    for (int m = 0; m < 4; m++)
        #pragma unroll
        for (int n = 0; n < 4; n++)
            acc[m][n] = (floatx4){0.f, 0.f, 0.f, 0.f};

    // fragment read bases (A: row = wr*64 + m*16 + (lane&15); k = ks*32 + (lane>>4)*8)
    const uint8_t* pa = &lsA[(size_t)((wr * 64) + (lane & 15)) * 64 + (lane >> 4) * 8];
    const uint8_t* pb = &lsB[(size_t)((wc * 64) + (lane & 15)) * 64 + (lane >> 4) * 8];

    for (int kt = 0; kt < K; kt += 64) {
        __builtin_amdgcn_global_load_lds(
            (const __attribute__((address_space(1))) void*)(ga + kt),
            (__attribute__((address_space(3))) void*)la, 16, 0, 0);
        __builtin_amdgcn_global_load_lds(
            (const __attribute__((address_space(1))) void*)(ga + kt + (size_t)64 * K),
            (__attribute__((address_space(3))) void*)(la + 4096), 16, 0, 0);
        __builtin_amdgcn_global_load_lds(
            (const __attribute__((address_space(1))) void*)(gb + kt),
            (__attribute__((address_space(3))) void*)lb, 16, 0, 0);
        __builtin_amdgcn_global_load_lds(
            (const __attribute__((address_space(1))) void*)(gb + kt + (size_t)64 * K),
            (__attribute__((address_space(3))) void*)(lb + 4096), 16, 0, 0);
        __syncthreads();   // compiler emits vmcnt(0) drain before barrier

        #pragma unroll
        for (int ks = 0; ks < 2; ks++) {
            long long af[4], bf[4];
            #pragma unroll
            for (int m = 0; m < 4; m++)
                af[m] = *(const long long*)(pa + m * 16 * 64 + ks * 32);
            #pragma unroll
            for (int n = 0; n < 4; n++)
                bf[n] = *(const long long*)(pb + n * 16 * 64 + ks * 32);
            #pragma unroll
            for (int m = 0; m < 4; m++)
                #pragma unroll
                for (int n = 0; n < 4; n++)
                    acc[m][n] = __builtin_amdgcn_mfma_f32_16x16x32_fp8_fp8(
                        af[m], bf[n], acc[m][n], 0, 0, 0);
        }
        __syncthreads();
    }

    float sxv = fmaxf(__uint_as_float(hdr[0]), QEPS) / F8MAX;
    float swv = fmaxf(__uint_as_float(hdr[1]), QEPS) / F8MAX;
    float s = sxv * swv;

    int col0 = bn * 128 + wc * 64 + (lane & 15);
    int row0 = bm * 128 + wr * 64 + ((lane >> 4) * 4);
    #pragma unroll
    for (int m = 0; m < 4; m++) {
        #pragma unroll
        for (int n = 0; n < 4; n++) {
            int col = col0 + n * 16;
            float bv = bias[col];
            #pragma unroll
            for (int j = 0; j < 4; j++) {
                int row = row0 + m * 16 + j;
                C[(size_t)row * N + col] = acc[m][n][j] * s + bv;
            }
        }
    }
}

extern "C" void kernel_launch(void* const* d_in, const int* in_sizes, int n_in,
                              void* d_out, int out_size, void* d_ws, size_t ws_size,
                              hipStream_t stream)
{
    const float* x    = (const float*)d_in[0];
    const float* w    = (const float*)d_in[1];
    const float* bias = (const float*)d_in[2];
    float* out = (float*)d_out;

    int N = in_sizes[2];                 // 1024
    int K = in_sizes[1] / N;             // 1024
    int M = in_sizes[0] / K;             // 65536
    int nx = in_sizes[0];                // 67,108,864
    int nw = in_sizes[1];                // 1,048,576

    // workspace layout
    uint8_t* ws = (uint8_t*)d_ws;
    unsigned* hdr = (unsigned*)ws;                    // [0]=amax_x bits, [1]=amax_w bits
    float* px = (float*)(ws + 64);                    // 1024 partials (x)
    float* pw = (float*)(ws + 64 + 4096);             // 256 partials (w)
    uint8_t* w8 = ws + 16384;                         // N*K bytes
    uint8_t* x8 = ws + 16384 + (size_t)N * K;         // M*K bytes

    const int AX_BLOCKS = 1024;
    const int AW_BLOCKS = 256;

    amax_partial<<<AX_BLOCKS, 256, 0, stream>>>(x, nx / 4, px);
    amax_partial<<<AW_BLOCKS, 256, 0, stream>>>(w, nw / 4, pw);
    final_reduce<<<1, 256, 0, stream>>>(px, AX_BLOCKS, pw, AW_BLOCKS, hdr);

    quant_fp8<<<(nx + 4095) / 4096, 256, 0, stream>>>(x, x8, hdr, 0, nx);
    quant_fp8<<<(nw + 4095) / 4096, 256, 0, stream>>>(w, w8, hdr, 1, nw);

    int nbm = M / 128, nbn = N / 128;
    int swz = (nbm % 8 == 0) ? 1 : 0;
    gemm_fp8<<<nbm * nbn, 256, 0, stream>>>(x8, w8, out, bias, hdr, M, N, K, nbn, swz);
}

// Round 2
// 343.943 us; speedup vs baseline: 1.0897x; 1.0897x over previous
//
#include <hip/hip_runtime.h>
#include <stdint.h>

#define F8MAX 448.0f
#define QEPS 1e-12f

typedef float floatx4 __attribute__((ext_vector_type(4)));
typedef long  longx2  __attribute__((ext_vector_type(2)));

// ---------------- pass 1: per-block amax partials ----------------
__global__ void amax_partial(const float* __restrict__ in, int n4, float* __restrict__ partial)
{
    const float4* in4 = (const float4*)in;
    int tid = blockIdx.x * blockDim.x + threadIdx.x;
    int stride = gridDim.x * blockDim.x;
    float m = 0.0f;
    for (int i = tid; i < n4; i += stride) {
        float4 v = in4[i];
        m = fmaxf(m, fmaxf(fmaxf(fabsf(v.x), fabsf(v.y)), fmaxf(fabsf(v.z), fabsf(v.w))));
    }
    #pragma unroll
    for (int off = 32; off > 0; off >>= 1)
        m = fmaxf(m, __shfl_xor(m, off, 64));
    __shared__ float sm[4];
    if ((threadIdx.x & 63) == 0) sm[threadIdx.x >> 6] = m;
    __syncthreads();
    if (threadIdx.x == 0)
        partial[blockIdx.x] = fmaxf(fmaxf(sm[0], sm[1]), fmaxf(sm[2], sm[3]));
}

// ---------------- pass 2: final reduce of both partial arrays ----------------
__global__ void final_reduce(const float* __restrict__ px, int nx,
                             const float* __restrict__ pw, int nw,
                             unsigned* __restrict__ hdr)
{
    float mx = 0.0f, mw = 0.0f;
    for (int i = threadIdx.x; i < nx; i += 256) mx = fmaxf(mx, px[i]);
    for (int i = threadIdx.x; i < nw; i += 256) mw = fmaxf(mw, pw[i]);
    #pragma unroll
    for (int off = 32; off > 0; off >>= 1) {
        mx = fmaxf(mx, __shfl_xor(mx, off, 64));
        mw = fmaxf(mw, __shfl_xor(mw, off, 64));
    }
    __shared__ float sx[4], sw[4];
    if ((threadIdx.x & 63) == 0) { sx[threadIdx.x >> 6] = mx; sw[threadIdx.x >> 6] = mw; }
    __syncthreads();
    if (threadIdx.x == 0) {
        float ax = fmaxf(fmaxf(sx[0], sx[1]), fmaxf(sx[2], sx[3]));
        float aw = fmaxf(fmaxf(sw[0], sw[1]), fmaxf(sw[2], sw[3]));
        hdr[0] = __float_as_uint(ax);
        hdr[1] = __float_as_uint(aw);
    }
}

// ---------------- pass 3: quantize fp32 -> fp8 e4m3 into fragment-scrambled layout ----------------
// Scrambled layout (per tensor with R rows, K cols, K%64==0, R%128==0):
//   fragment (row, j8) = 8 consecutive fp8 of row `row`, k in [j8*8, j8*8+8), within k-tile kt.
//   p = row>>7, r = row&127, kt = k>>6, q = j8&3, hi = j8>>2
//   byte offset = ((p*nkt + kt)*8192) + q*2048 + r*16 + hi*8 + (k&7)
// => each 16B word holds BOTH ks=0 (j8=q) and ks=1 (j8=q+4) fragments for (r, q):
//    exactly the two MFMA A/B fragments one lane needs for one 64-wide K-step.
__global__ void quant_scramble(const float* __restrict__ in, uint8_t* __restrict__ out,
                               const unsigned* __restrict__ hdr, int hidx, int nkt, int K)
{
    int bid = blockIdx.x;
    int p  = bid / nkt;
    int kt = bid - p * nkt;
    float amax = __uint_as_float(hdr[hidx]);
    float scale = fmaxf(amax, QEPS) / F8MAX;   // true fp32 division (matches ref)

    uint8_t* dst = out + (size_t)bid * 8192;

    #pragma unroll
    for (int i = 0; i < 2; i++) {
        int b16 = threadIdx.x + i * 256;       // 0..511
        int q = b16 >> 7;                      // 0..3
        int r = b16 & 127;
        const float* src = in + (size_t)(p * 128 + r) * K + kt * 64 + q * 8;
        float4 f0 = *(const float4*)(src);
        float4 f1 = *(const float4*)(src + 4);
        float4 f2 = *(const float4*)(src + 32);
        float4 f3 = *(const float4*)(src + 36);
        int w0 = 0, w1 = 0, w2 = 0, w3 = 0;
        w0 = __builtin_amdgcn_cvt_pk_fp8_f32(f0.x / scale, f0.y / scale, w0, false);
        w0 = __builtin_amdgcn_cvt_pk_fp8_f32(f0.z / scale, f0.w / scale, w0, true);
        w1 = __builtin_amdgcn_cvt_pk_fp8_f32(f1.x / scale, f1.y / scale, w1, false);
        w1 = __builtin_amdgcn_cvt_pk_fp8_f32(f1.z / scale, f1.w / scale, w1, true);
        w2 = __builtin_amdgcn_cvt_pk_fp8_f32(f2.x / scale, f2.y / scale, w2, false);
        w2 = __builtin_amdgcn_cvt_pk_fp8_f32(f2.z / scale, f2.w / scale, w2, true);
        w3 = __builtin_amdgcn_cvt_pk_fp8_f32(f3.x / scale, f3.y / scale, w3, false);
        w3 = __builtin_amdgcn_cvt_pk_fp8_f32(f3.z / scale, f3.w / scale, w3, true);
        int4 rv; rv.x = w0; rv.y = w1; rv.z = w2; rv.w = w3;
        *(int4*)(dst + (size_t)b16 * 16) = rv;   // perfectly coalesced
    }
}

// ---------------- pass 4: fp8 GEMM, m97 structure, conflict-free scrambled LDS ----------------
// C[M,N] = (A8[M,K] . B8[N,K]^T) * s + bias[N];  A8/B8 in scrambled layout.
__global__ __launch_bounds__(256) void gemm_fp8(
    const uint8_t* __restrict__ A8, const uint8_t* __restrict__ B8,
    float* __restrict__ C, const float* __restrict__ bias,
    const unsigned* __restrict__ hdr, int N, int K, int nkt, int nbn, int swz)
{
    __shared__ uint8_t lsA[8192];
    __shared__ uint8_t lsB[8192];

    int bid = blockIdx.x;
    int bm, bn;
    if (swz) {
        int grp = bid / (8 * nbn);
        int within = bid - grp * (8 * nbn);
        bm = grp * 8 + (within & 7);
        bn = within >> 3;
    } else {
        bm = bid / nbn;
        bn = bid - bm * nbn;
    }

    int t = threadIdx.x;
    int wave = t >> 6;
    int lane = t & 63;
    int wr = wave >> 1, wc = wave & 1;

    // linear staging: tile (bm, kt) occupies 8192 contiguous bytes in scrambled global
    const uint8_t* gA = A8 + (size_t)bm * nkt * 8192 + wave * 1024 + lane * 16;
    const uint8_t* gB = B8 + (size_t)bn * nkt * 8192 + wave * 1024 + lane * 16;
    uint8_t* la = &lsA[wave * 1024];
    uint8_t* lb = &lsB[wave * 1024];

    floatx4 acc[4][4];
    #pragma unroll
    for (int m = 0; m < 4; m++)
        #pragma unroll
        for (int n = 0; n < 4; n++)
            acc[m][n] = (floatx4){0.f, 0.f, 0.f, 0.f};

    // fragment read bases: addr(row, q) = q*2048 + row*16; one b128 = ks0|ks1 frags
    const uint8_t* pa = &lsA[(lane >> 4) * 2048 + (wr * 64 + (lane & 15)) * 16];
    const uint8_t* pb = &lsB[(lane >> 4) * 2048 + (wc * 64 + (lane & 15)) * 16];

    for (int kt = 0; kt < nkt; kt++) {
        __builtin_amdgcn_global_load_lds(
            (const __attribute__((address_space(1))) void*)(gA + (size_t)kt * 8192),
            (__attribute__((address_space(3))) void*)la, 16, 0, 0);
        __builtin_amdgcn_global_load_lds(
            (const __attribute__((address_space(1))) void*)(gA + (size_t)kt * 8192 + 4096),
            (__attribute__((address_space(3))) void*)(la + 4096), 16, 0, 0);
        __builtin_amdgcn_global_load_lds(
            (const __attribute__((address_space(1))) void*)(gB + (size_t)kt * 8192),
            (__attribute__((address_space(3))) void*)lb, 16, 0, 0);
        __builtin_amdgcn_global_load_lds(
            (const __attribute__((address_space(1))) void*)(gB + (size_t)kt * 8192 + 4096),
            (__attribute__((address_space(3))) void*)(lb + 4096), 16, 0, 0);
        __syncthreads();

        longx2 af[4], bf[4];
        #pragma unroll
        for (int m = 0; m < 4; m++)
            af[m] = *(const longx2*)(pa + m * 256);
        #pragma unroll
        for (int n = 0; n < 4; n++)
            bf[n] = *(const longx2*)(pb + n * 256);
        #pragma unroll
        for (int m = 0; m < 4; m++)
            #pragma unroll
            for (int n = 0; n < 4; n++) {
                acc[m][n] = __builtin_amdgcn_mfma_f32_16x16x32_fp8_fp8(
                    af[m].x, bf[n].x, acc[m][n], 0, 0, 0);
                acc[m][n] = __builtin_amdgcn_mfma_f32_16x16x32_fp8_fp8(
                    af[m].y, bf[n].y, acc[m][n], 0, 0, 0);
            }
        __syncthreads();
    }

    float sxv = fmaxf(__uint_as_float(hdr[0]), QEPS) / F8MAX;
    float swv = fmaxf(__uint_as_float(hdr[1]), QEPS) / F8MAX;
    float s = sxv * swv;

    int col0 = bn * 128 + wc * 64 + (lane & 15);
    int row0 = bm * 128 + wr * 64 + ((lane >> 4) * 4);
    #pragma unroll
    for (int m = 0; m < 4; m++) {
        #pragma unroll
        for (int n = 0; n < 4; n++) {
            int col = col0 + n * 16;
            float bv = bias[col];
            #pragma unroll
            for (int j = 0; j < 4; j++) {
                int row = row0 + m * 16 + j;
                C[(size_t)row * N + col] = acc[m][n][j] * s + bv;
            }
        }
    }
}

extern "C" void kernel_launch(void* const* d_in, const int* in_sizes, int n_in,
                              void* d_out, int out_size, void* d_ws, size_t ws_size,
                              hipStream_t stream)
{
    const float* x    = (const float*)d_in[0];
    const float* w    = (const float*)d_in[1];
    const float* bias = (const float*)d_in[2];
    float* out = (float*)d_out;

    int N = in_sizes[2];                 // 1024
    int K = in_sizes[1] / N;             // 1024
    int M = in_sizes[0] / K;             // 65536
    int nx = in_sizes[0];                // 67,108,864
    int nw = in_sizes[1];                // 1,048,576
    int nkt = K / 64;                    // 16

    // workspace layout
    uint8_t* ws = (uint8_t*)d_ws;
    unsigned* hdr = (unsigned*)ws;                    // [0]=amax_x bits, [1]=amax_w bits
    float* px = (float*)(ws + 64);                    // 1024 partials (x)
    float* pw = (float*)(ws + 64 + 4096);             // 256 partials (w)
    uint8_t* w8 = ws + 16384;                         // N*K bytes (scrambled)
    uint8_t* x8 = ws + 16384 + (size_t)N * K;         // M*K bytes (scrambled)

    const int AX_BLOCKS = 1024;
    const int AW_BLOCKS = 256;

    amax_partial<<<AX_BLOCKS, 256, 0, stream>>>(x, nx / 4, px);
    amax_partial<<<AW_BLOCKS, 256, 0, stream>>>(w, nw / 4, pw);
    final_reduce<<<1, 256, 0, stream>>>(px, AX_BLOCKS, pw, AW_BLOCKS, hdr);

    quant_scramble<<<(M / 128) * nkt, 256, 0, stream>>>(x, x8, hdr, 0, nkt, K);
    quant_scramble<<<(N / 128) * nkt, 256, 0, stream>>>(w, w8, hdr, 1, nkt, K);

    int nbm = M / 128, nbn = N / 128;
    int swz = (nbm % 8 == 0) ? 1 : 0;
    gemm_fp8<<<nbm * nbn, 256, 0, stream>>>(x8, w8, out, bias, hdr, N, K, nkt, nbn, swz);
}

// Round 3
// 297.878 us; speedup vs baseline: 1.2583x; 1.1546x over previous
//
#include <hip/hip_runtime.h>
#include <stdint.h>

#define F8MAX 448.0f
#define QEPS 1e-12f

typedef float floatx4 __attribute__((ext_vector_type(4)));
typedef long  longx2  __attribute__((ext_vector_type(2)));

// ---------------- pass 1: per-block amax partials ----------------
__global__ void amax_partial(const float* __restrict__ in, int n4, float* __restrict__ partial)
{
    const float4* in4 = (const float4*)in;
    int tid = blockIdx.x * blockDim.x + threadIdx.x;
    int stride = gridDim.x * blockDim.x;
    float m = 0.0f;
    for (int i = tid; i < n4; i += stride) {
        float4 v = in4[i];
        m = fmaxf(m, fmaxf(fmaxf(fabsf(v.x), fabsf(v.y)), fmaxf(fabsf(v.z), fabsf(v.w))));
    }
    #pragma unroll
    for (int off = 32; off > 0; off >>= 1)
        m = fmaxf(m, __shfl_xor(m, off, 64));
    __shared__ float sm[4];
    if ((threadIdx.x & 63) == 0) sm[threadIdx.x >> 6] = m;
    __syncthreads();
    if (threadIdx.x == 0)
        partial[blockIdx.x] = fmaxf(fmaxf(sm[0], sm[1]), fmaxf(sm[2], sm[3]));
}

// ---------------- pass 2: final reduce of both partial arrays ----------------
__global__ void final_reduce(const float* __restrict__ px, int nx,
                             const float* __restrict__ pw, int nw,
                             unsigned* __restrict__ hdr)
{
    float mx = 0.0f, mw = 0.0f;
    for (int i = threadIdx.x; i < nx; i += 256) mx = fmaxf(mx, px[i]);
    for (int i = threadIdx.x; i < nw; i += 256) mw = fmaxf(mw, pw[i]);
    #pragma unroll
    for (int off = 32; off > 0; off >>= 1) {
        mx = fmaxf(mx, __shfl_xor(mx, off, 64));
        mw = fmaxf(mw, __shfl_xor(mw, off, 64));
    }
    __shared__ float sx[4], sw[4];
    if ((threadIdx.x & 63) == 0) { sx[threadIdx.x >> 6] = mx; sw[threadIdx.x >> 6] = mw; }
    __syncthreads();
    if (threadIdx.x == 0) {
        hdr[0] = __float_as_uint(fmaxf(fmaxf(sx[0], sx[1]), fmaxf(sx[2], sx[3])));
        hdr[1] = __float_as_uint(fmaxf(fmaxf(sw[0], sw[1]), fmaxf(sw[2], sw[3])));
    }
}

// ---------------- pass 3: quantize fp32 -> fp8 e4m3 into fragment-scrambled layout ----------------
// byte offset = ((p*nkt + kt)*8192) + q*2048 + r*16 + hi*8 + (k&7)
// (panel p = row>>7, r = row&127, kt = k>>6, q = (k>>3)&3, hi = k>>5 within tile)
// Each 16B word holds both ks=0 and ks=1 MFMA fragments for (row r, k-quarter q).
__global__ void quant_scramble(const float* __restrict__ in, uint8_t* __restrict__ out,
                               const unsigned* __restrict__ hdr, int hidx, int nkt, int K, int rev)
{
    int bid = blockIdx.x;
    if (rev) bid = gridDim.x - 1 - bid;   // back-to-front: re-hit the L3 lines amax just streamed
    int p  = bid / nkt;
    int kt = bid - p * nkt;
    float amax = __uint_as_float(hdr[hidx]);
    float scale = fmaxf(amax, QEPS) / F8MAX;   // true fp32 division (matches ref)

    uint8_t* dst = out + (size_t)bid * 8192;

    #pragma unroll
    for (int i = 0; i < 2; i++) {
        int b16 = threadIdx.x + i * 256;       // 0..511
        int q = b16 >> 7;                      // 0..3
        int r = b16 & 127;
        const float* src = in + (size_t)(p * 128 + r) * K + kt * 64 + q * 8;
        float4 f0 = *(const float4*)(src);
        float4 f1 = *(const float4*)(src + 4);
        float4 f2 = *(const float4*)(src + 32);
        float4 f3 = *(const float4*)(src + 36);
        int w0 = 0, w1 = 0, w2 = 0, w3 = 0;
        w0 = __builtin_amdgcn_cvt_pk_fp8_f32(f0.x / scale, f0.y / scale, w0, false);
        w0 = __builtin_amdgcn_cvt_pk_fp8_f32(f0.z / scale, f0.w / scale, w0, true);
        w1 = __builtin_amdgcn_cvt_pk_fp8_f32(f1.x / scale, f1.y / scale, w1, false);
        w1 = __builtin_amdgcn_cvt_pk_fp8_f32(f1.z / scale, f1.w / scale, w1, true);
        w2 = __builtin_amdgcn_cvt_pk_fp8_f32(f2.x / scale, f2.y / scale, w2, false);
        w2 = __builtin_amdgcn_cvt_pk_fp8_f32(f2.z / scale, f2.w / scale, w2, true);
        w3 = __builtin_amdgcn_cvt_pk_fp8_f32(f3.x / scale, f3.y / scale, w3, false);
        w3 = __builtin_amdgcn_cvt_pk_fp8_f32(f3.z / scale, f3.w / scale, w3, true);
        int4 rv; rv.x = w0; rv.y = w1; rv.z = w2; rv.w = w3;
        *(int4*)(dst + (size_t)b16 * 16) = rv;
    }
}

// ---------------- pass 4: fp8 GEMM, 256^2 tile, 4-phase counted-vmcnt pipeline ----------------
// C[M,N] = (A8 . B8^T) * s + bias[N]; A8/B8 scrambled; 8 waves (2M x 4N), BK=64, 3 LDS buffers.
__global__ __launch_bounds__(512, 2) void gemm_fp8_pipe(
    const uint8_t* __restrict__ A8, const uint8_t* __restrict__ B8,
    float* __restrict__ C, const float* __restrict__ bias,
    const unsigned* __restrict__ hdr, int N, int nkt, int nbn)
{
    __shared__ uint8_t lsA[3 * 16384];
    __shared__ uint8_t lsB[3 * 16384];

    // XCD-chunked bijective swizzle (grid % 8 == 0): each XCD gets a contiguous bm range
    int nwg = gridDim.x;
    int bid = blockIdx.x;
    if ((nwg & 7) == 0) {
        int chunk = nwg >> 3;
        bid = (blockIdx.x & 7) * chunk + (blockIdx.x >> 3);
    }
    int bm = bid / nbn, bn = bid - bm * nbn;

    int t = threadIdx.x;
    int wave = t >> 6, lane = t & 63;
    int wr = wave >> 2, wc = wave & 3;        // 2(M) x 4(N)
    int q = lane >> 4, r15 = lane & 15;

    // ---- staging chunk map: 32 x 1KB chunks per K-tile; wave v owns chunks v*4+p ----
    const uint8_t* gsrc0; const uint8_t* gsrc1; const uint8_t* gsrc2; const uint8_t* gsrc3;
    uint32_t ld0, ld1, ld2, ld3;
    bool isA = (wave < 4);
    {
        int c0 = wave * 4;
        #pragma unroll
        for (int p = 0; p < 4; p++) {
            int c = c0 + p;
            const uint8_t* g;
            uint32_t l;
            if (c < 16) {
                int h = c >> 3, sub = c & 7;
                g = A8 + (size_t)(bm * 2 + h) * nkt * 8192 + sub * 1024 + lane * 16;
                l = (uint32_t)c * 1024;
            } else {
                int cc = c - 16, h = cc >> 3, sub = cc & 7;
                g = B8 + (size_t)(bn * 2 + h) * nkt * 8192 + sub * 1024 + lane * 16;
                l = (uint32_t)cc * 1024;
            }
            if (p == 0) { gsrc0 = g; ld0 = l; }
            else if (p == 1) { gsrc1 = g; ld1 = l; }
            else if (p == 2) { gsrc2 = g; ld2 = l; }
            else { gsrc3 = g; ld3 = l; }
        }
    }
    uint8_t* lsbase = isA ? lsA : lsB;

#define ISSUE(GP, LO, KT2, B2)                                                   \
    __builtin_amdgcn_global_load_lds(                                            \
        (const __attribute__((address_space(1))) void*)((GP) + (size_t)(KT2) * 8192), \
        (__attribute__((address_space(3))) void*)(lsbase + (B2) * 16384 + (LO)), \
        16, 0, 0)

    // fragment read bases
    const uint8_t* baseA = lsA + wr * 8192 + q * 2048 + r15 * 16;
    const uint8_t* baseB = lsB + (wc >> 1) * 8192 + q * 2048 + (((wc & 1) * 64 + r15) * 16);

    floatx4 acc[8][4];
    #pragma unroll
    for (int m = 0; m < 8; m++)
        #pragma unroll
        for (int n = 0; n < 4; n++)
            acc[m][n] = (floatx4){0.f, 0.f, 0.f, 0.f};

#define MM(m, n)                                                                      \
    acc[m][n] = __builtin_amdgcn_mfma_f32_16x16x32_fp8_fp8(af[m].x, bf[n].x, acc[m][n], 0, 0, 0); \
    acc[m][n] = __builtin_amdgcn_mfma_f32_16x16x32_fp8_fp8(af[m].y, bf[n].y, acc[m][n], 0, 0, 0)

    // ---- prologue: stage tiles 0 and 1 ----
    ISSUE(gsrc0, ld0, 0, 0); ISSUE(gsrc1, ld1, 0, 0); ISSUE(gsrc2, ld2, 0, 0); ISSUE(gsrc3, ld3, 0, 0);
    if (nkt > 1) {
        ISSUE(gsrc0, ld0, 1, 1); ISSUE(gsrc1, ld1, 1, 1); ISSUE(gsrc2, ld2, 1, 1); ISSUE(gsrc3, ld3, 1, 1);
        asm volatile("s_waitcnt vmcnt(4)" ::: "memory");
    } else {
        asm volatile("s_waitcnt vmcnt(0)" ::: "memory");
    }
    asm volatile("s_barrier" ::: "memory");

    int cur = 0;
    for (int kt = 0; kt < nkt; kt++) {
        bool pf = (kt + 2 < nkt);
        int ib = cur - 1; if (ib < 0) ib += 3;          // (kt+2) % 3
        const uint8_t* cA = baseA + cur * 16384;
        const uint8_t* cB = baseB + cur * 16384;
        longx2 af[8], bf[4];

        // ---- phase 0: A m0-3, B n0-1 ----
        if (pf) ISSUE(gsrc0, ld0, kt + 2, ib);
        #pragma unroll
        for (int m = 0; m < 4; m++) af[m] = *(const longx2*)(cA + m * 256);
        bf[0] = *(const longx2*)(cB);
        bf[1] = *(const longx2*)(cB + 256);
        asm volatile("s_barrier" ::: "memory");
        __builtin_amdgcn_s_setprio(1);
        MM(0, 0); MM(1, 0); MM(2, 0); MM(3, 0);
        MM(0, 1); MM(1, 1); MM(2, 1); MM(3, 1);
        __builtin_amdgcn_s_setprio(0);
        asm volatile("s_barrier" ::: "memory");

        // ---- phase 1: A m4-7 ----
        if (pf) ISSUE(gsrc1, ld1, kt + 2, ib);
        #pragma unroll
        for (int m = 4; m < 8; m++) af[m] = *(const longx2*)(cA + m * 256);
        asm volatile("s_barrier" ::: "memory");
        __builtin_amdgcn_s_setprio(1);
        MM(4, 0); MM(5, 0); MM(6, 0); MM(7, 0);
        MM(4, 1); MM(5, 1); MM(6, 1); MM(7, 1);
        __builtin_amdgcn_s_setprio(0);
        asm volatile("s_barrier" ::: "memory");

        // ---- phase 2: B n2-3 ----
        if (pf) ISSUE(gsrc2, ld2, kt + 2, ib);
        bf[2] = *(const longx2*)(cB + 512);
        bf[3] = *(const longx2*)(cB + 768);
        asm volatile("s_barrier" ::: "memory");
        __builtin_amdgcn_s_setprio(1);
        MM(0, 2); MM(1, 2); MM(2, 2); MM(3, 2);
        MM(0, 3); MM(1, 3); MM(2, 3); MM(3, 3);
        __builtin_amdgcn_s_setprio(0);
        asm volatile("s_barrier" ::: "memory");

        // ---- phase 3 ----
        if (pf) ISSUE(gsrc3, ld3, kt + 2, ib);
        asm volatile("s_barrier" ::: "memory");
        __builtin_amdgcn_s_setprio(1);
        MM(4, 2); MM(5, 2); MM(6, 2); MM(7, 2);
        MM(4, 3); MM(5, 3); MM(6, 3); MM(7, 3);
        __builtin_amdgcn_s_setprio(0);
        if (pf) asm volatile("s_waitcnt vmcnt(4)" ::: "memory");
        else    asm volatile("s_waitcnt vmcnt(0)" ::: "memory");
        asm volatile("s_barrier" ::: "memory");

        cur++; if (cur == 3) cur = 0;
    }

    float sxv = fmaxf(__uint_as_float(hdr[0]), QEPS) / F8MAX;
    float swv = fmaxf(__uint_as_float(hdr[1]), QEPS) / F8MAX;
    float s = sxv * swv;

    int col0 = bn * 256 + wc * 64 + r15;
    int row0 = bm * 256 + wr * 128 + q * 4;
    #pragma unroll
    for (int n = 0; n < 4; n++) {
        int col = col0 + n * 16;
        float bv = bias[col];
        #pragma unroll
        for (int m = 0; m < 8; m++) {
            #pragma unroll
            for (int j = 0; j < 4; j++) {
                int row = row0 + m * 16 + j;
                C[(size_t)row * N + col] = acc[m][n][j] * s + bv;
            }
        }
    }
#undef ISSUE
#undef MM
}

extern "C" void kernel_launch(void* const* d_in, const int* in_sizes, int n_in,
                              void* d_out, int out_size, void* d_ws, size_t ws_size,
                              hipStream_t stream)
{
    const float* x    = (const float*)d_in[0];
    const float* w    = (const float*)d_in[1];
    const float* bias = (const float*)d_in[2];
    float* out = (float*)d_out;

    int N = in_sizes[2];                 // 1024
    int K = in_sizes[1] / N;             // 1024
    int M = in_sizes[0] / K;             // 65536
    int nx = in_sizes[0];
    int nw = in_sizes[1];
    int nkt = K / 64;                    // 16

    uint8_t* ws = (uint8_t*)d_ws;
    unsigned* hdr = (unsigned*)ws;
    float* px = (float*)(ws + 64);
    float* pw = (float*)(ws + 64 + 4096);
    uint8_t* w8 = ws + 16384;
    uint8_t* x8 = ws + 16384 + (size_t)N * K;

    const int AX_BLOCKS = 1024;
    const int AW_BLOCKS = 256;

    amax_partial<<<AX_BLOCKS, 256, 0, stream>>>(x, nx / 4, px);
    amax_partial<<<AW_BLOCKS, 256, 0, stream>>>(w, nw / 4, pw);
    final_reduce<<<1, 256, 0, stream>>>(px, AX_BLOCKS, pw, AW_BLOCKS, hdr);

    quant_scramble<<<(M / 128) * nkt, 256, 0, stream>>>(x, x8, hdr, 0, nkt, K, 1);
    quant_scramble<<<(N / 128) * nkt, 256, 0, stream>>>(w, w8, hdr, 1, nkt, K, 0);

    int nbm = M / 256, nbn = N / 256;
    gemm_fp8_pipe<<<nbm * nbn, 512, 0, stream>>>(x8, w8, out, bias, hdr, N, nkt, nbn);
}

// Round 4
// 245.314 us; speedup vs baseline: 1.5279x; 1.2143x over previous
//
#include <hip/hip_runtime.h>
#include <stdint.h>

#define F8MAX 448.0f
#define QEPS 1e-12f
#define SCL_ONE 0x7F7F7F7F   // E8M0 exponent 127 => 2^0 = 1.0 per byte

typedef float floatx16 __attribute__((ext_vector_type(16)));
typedef int   intx4    __attribute__((ext_vector_type(4)));
typedef int   intx8    __attribute__((ext_vector_type(8)));

// ---------------- pass 1: per-block amax partials ----------------
__global__ void amax_partial(const float* __restrict__ in, int n4, float* __restrict__ partial)
{
    const float4* in4 = (const float4*)in;
    int tid = blockIdx.x * blockDim.x + threadIdx.x;
    int stride = gridDim.x * blockDim.x;
    float m = 0.0f;
    for (int i = tid; i < n4; i += stride) {
        float4 v = in4[i];
        m = fmaxf(m, fmaxf(fmaxf(fabsf(v.x), fabsf(v.y)), fmaxf(fabsf(v.z), fabsf(v.w))));
    }
    #pragma unroll
    for (int off = 32; off > 0; off >>= 1)
        m = fmaxf(m, __shfl_xor(m, off, 64));
    __shared__ float sm[4];
    if ((threadIdx.x & 63) == 0) sm[threadIdx.x >> 6] = m;
    __syncthreads();
    if (threadIdx.x == 0)
        partial[blockIdx.x] = fmaxf(fmaxf(sm[0], sm[1]), fmaxf(sm[2], sm[3]));
}

// ---------------- pass 2: final reduce of both partial arrays ----------------
__global__ void final_reduce(const float* __restrict__ px, int nx,
                             const float* __restrict__ pw, int nw,
                             unsigned* __restrict__ hdr)
{
    float mx = 0.0f, mw = 0.0f;
    for (int i = threadIdx.x; i < nx; i += 256) mx = fmaxf(mx, px[i]);
    for (int i = threadIdx.x; i < nw; i += 256) mw = fmaxf(mw, pw[i]);
    #pragma unroll
    for (int off = 32; off > 0; off >>= 1) {
        mx = fmaxf(mx, __shfl_xor(mx, off, 64));
        mw = fmaxf(mw, __shfl_xor(mw, off, 64));
    }
    __shared__ float sx[4], sw[4];
    if ((threadIdx.x & 63) == 0) { sx[threadIdx.x >> 6] = mx; sw[threadIdx.x >> 6] = mw; }
    __syncthreads();
    if (threadIdx.x == 0) {
        hdr[0] = __float_as_uint(fmaxf(fmaxf(sx[0], sx[1]), fmaxf(sx[2], sx[3])));
        hdr[1] = __float_as_uint(fmaxf(fmaxf(sw[0], sw[1]), fmaxf(sw[2], sw[3])));
    }
}

// ---------------- pass 3: quantize fp32 -> fp8 e4m3 into MX-fragment-scrambled layout ----------
// Per (128-row panel p, 64-col k-tile kt): 8192-byte block. Element (r, k):
//   h = k>>5 (lane-half), pc = (k>>4)&1 (b128 piece), b = k&15
//   byte offset = h*4096 + pc*2048 + r*16 + b
// Lane of 32x32x64 f8f6f4 MFMA (row r' = l&31, k = (l>>5)*32 + j) then reads two b128s at
// (h=l>>5, pc=0/1, r) -> operand bytes j = pc*16 + b, i.e. 32 consecutive k. Conflict-free:
// 16 consecutive lanes read 256B contiguous LDS.
__global__ void quant_scramble(const float* __restrict__ in, uint8_t* __restrict__ out,
                               const unsigned* __restrict__ hdr, int hidx, int nkt, int K, int rev)
{
    int bid = blockIdx.x;
    if (rev) bid = gridDim.x - 1 - bid;   // back-to-front: re-hit L3 lines amax just streamed
    int p  = bid / nkt;
    int kt = bid - p * nkt;
    float amax = __uint_as_float(hdr[hidx]);
    float scale = fmaxf(amax, QEPS) / F8MAX;   // true fp32 division (matches ref)

    uint8_t* dst = out + (size_t)bid * 8192;

    #pragma unroll
    for (int i = 0; i < 2; i++) {
        int idx = threadIdx.x + i * 256;       // 0..511
        int h  = idx >> 8;
        int pc = (idx >> 7) & 1;
        int r  = idx & 127;
        const float* src = in + (size_t)(p * 128 + r) * K + kt * 64 + h * 32 + pc * 16;
        float4 f0 = *(const float4*)(src);
        float4 f1 = *(const float4*)(src + 4);
        float4 f2 = *(const float4*)(src + 8);
        float4 f3 = *(const float4*)(src + 12);
        int w0 = 0, w1 = 0, w2 = 0, w3 = 0;
        w0 = __builtin_amdgcn_cvt_pk_fp8_f32(f0.x / scale, f0.y / scale, w0, false);
        w0 = __builtin_amdgcn_cvt_pk_fp8_f32(f0.z / scale, f0.w / scale, w0, true);
        w1 = __builtin_amdgcn_cvt_pk_fp8_f32(f1.x / scale, f1.y / scale, w1, false);
        w1 = __builtin_amdgcn_cvt_pk_fp8_f32(f1.z / scale, f1.w / scale, w1, true);
        w2 = __builtin_amdgcn_cvt_pk_fp8_f32(f2.x / scale, f2.y / scale, w2, false);
        w2 = __builtin_amdgcn_cvt_pk_fp8_f32(f2.z / scale, f2.w / scale, w2, true);
        w3 = __builtin_amdgcn_cvt_pk_fp8_f32(f3.x / scale, f3.y / scale, w3, false);
        w3 = __builtin_amdgcn_cvt_pk_fp8_f32(f3.z / scale, f3.w / scale, w3, true);
        int4 rv; rv.x = w0; rv.y = w1; rv.z = w2; rv.w = w3;
        *(int4*)(dst + (size_t)idx * 16) = rv;
    }
}

// ---------------- pass 4: MX-scaled fp8 GEMM (identity scales), 256^2 tile ----------------
// C[M,N] = (A8 . B8^T) * s + bias[N]; 8 waves (2M x 4N), BK=64, 3 LDS buffers, prefetch 2 ahead.
__global__ __launch_bounds__(512, 1) void gemm_fp8_mx(
    const uint8_t* __restrict__ A8, const uint8_t* __restrict__ B8,
    float* __restrict__ C, const float* __restrict__ bias,
    const unsigned* __restrict__ hdr, int N, int nkt, int nbn)
{
    __shared__ uint8_t lsA[3 * 16384];
    __shared__ uint8_t lsB[3 * 16384];

    // XCD-chunked bijective swizzle (grid % 8 == 0): each XCD gets a contiguous bm range
    int nwg = gridDim.x;
    int bid = blockIdx.x;
    if ((nwg & 7) == 0) {
        int chunk = nwg >> 3;
        bid = (blockIdx.x & 7) * chunk + (blockIdx.x >> 3);
    }
    int bm = bid / nbn, bn = bid - bm * nbn;

    int t = threadIdx.x;
    int wave = t >> 6, lane = t & 63;
    int wr = wave >> 2, wc = wave & 3;        // 2(M) x 4(N)
    int hl = lane >> 5, l31 = lane & 31;

    // ---- staging chunk map: 32 x 1KB chunks per K-tile; wave v owns chunks v*4+p ----
    const uint8_t* gsrc0; const uint8_t* gsrc1; const uint8_t* gsrc2; const uint8_t* gsrc3;
    uint32_t ld0, ld1, ld2, ld3;
    bool isA = (wave < 4);
    {
        int c0 = wave * 4;
        #pragma unroll
        for (int p = 0; p < 4; p++) {
            int c = c0 + p;
            const uint8_t* g;
            uint32_t l;
            if (c < 16) {
                int h = c >> 3, sub = c & 7;
                g = A8 + (size_t)(bm * 2 + h) * nkt * 8192 + sub * 1024 + lane * 16;
                l = (uint32_t)c * 1024;
            } else {
                int cc = c - 16, h = cc >> 3, sub = cc & 7;
                g = B8 + (size_t)(bn * 2 + h) * nkt * 8192 + sub * 1024 + lane * 16;
                l = (uint32_t)cc * 1024;
            }
            if (p == 0) { gsrc0 = g; ld0 = l; }
            else if (p == 1) { gsrc1 = g; ld1 = l; }
            else if (p == 2) { gsrc2 = g; ld2 = l; }
            else { gsrc3 = g; ld3 = l; }
        }
    }
    uint8_t* lsbase = isA ? lsA : lsB;

#define ISSUE(GP, LO, KT2, B2)                                                   \
    __builtin_amdgcn_global_load_lds(                                            \
        (const __attribute__((address_space(1))) void*)((GP) + (size_t)(KT2) * 8192), \
        (__attribute__((address_space(3))) void*)(lsbase + (B2) * 16384 + (LO)), \
        16, 0, 0)

    // fragment read bases
    const uint8_t* baseA = lsA + wr * 8192 + hl * 4096 + l31 * 16;
    const uint8_t* baseB = lsB + (wc >> 1) * 8192 + hl * 4096 + (wc & 1) * 1024 + l31 * 16;

    floatx16 acc[4][2];
    #pragma unroll
    for (int m = 0; m < 4; m++)
        #pragma unroll
        for (int n = 0; n < 2; n++)
            acc[m][n] = (floatx16)(0.0f);

#define RD8(BASE, OFF) __builtin_shufflevector(                         \
        *(const intx4*)((BASE) + (OFF)),                                \
        *(const intx4*)((BASE) + (OFF) + 2048), 0, 1, 2, 3, 4, 5, 6, 7)

#define MMX(m, n) acc[m][n] = __builtin_amdgcn_mfma_scale_f32_32x32x64_f8f6f4( \
        af[m], bf[n], acc[m][n], 0, 0, 0, SCL_ONE, 0, SCL_ONE)

    // ---- prologue: stage tiles 0 and 1 ----
    ISSUE(gsrc0, ld0, 0, 0); ISSUE(gsrc1, ld1, 0, 0); ISSUE(gsrc2, ld2, 0, 0); ISSUE(gsrc3, ld3, 0, 0);
    ISSUE(gsrc0, ld0, 1, 1); ISSUE(gsrc1, ld1, 1, 1); ISSUE(gsrc2, ld2, 1, 1); ISSUE(gsrc3, ld3, 1, 1);
    asm volatile("s_waitcnt vmcnt(4)" ::: "memory");
    asm volatile("s_barrier" ::: "memory");

    int cur = 0;
    for (int kt = 0; kt < nkt; kt++) {
        bool pf = (kt + 2 < nkt);
        int ib = cur - 1; if (ib < 0) ib += 3;          // (kt+2) % 3
        const uint8_t* cA = baseA + cur * 16384;
        const uint8_t* cB = baseB + cur * 16384;
        intx8 af[4], bf[2];

        // ---- phase 0: A m0-1, B n0-1 -> 4 MFMA ----
        if (pf) { ISSUE(gsrc0, ld0, kt + 2, ib); ISSUE(gsrc1, ld1, kt + 2, ib); }
        af[0] = RD8(cA, 0);
        af[1] = RD8(cA, 512);
        bf[0] = RD8(cB, 0);
        bf[1] = RD8(cB, 512);
        asm volatile("s_barrier" ::: "memory");
        __builtin_amdgcn_s_setprio(1);
        MMX(0, 0); MMX(0, 1); MMX(1, 0); MMX(1, 1);
        __builtin_amdgcn_s_setprio(0);
        asm volatile("s_barrier" ::: "memory");

        // ---- phase 1: A m2-3 -> 4 MFMA ----
        if (pf) { ISSUE(gsrc2, ld2, kt + 2, ib); ISSUE(gsrc3, ld3, kt + 2, ib); }
        af[2] = RD8(cA, 1024);
        af[3] = RD8(cA, 1536);
        asm volatile("s_barrier" ::: "memory");
        __builtin_amdgcn_s_setprio(1);
        MMX(2, 0); MMX(2, 1); MMX(3, 0); MMX(3, 1);
        __builtin_amdgcn_s_setprio(0);
        if (pf) asm volatile("s_waitcnt vmcnt(4)" ::: "memory");
        else    asm volatile("s_waitcnt vmcnt(0)" ::: "memory");
        asm volatile("s_barrier" ::: "memory");

        cur++; if (cur == 3) cur = 0;
    }

    float sxv = fmaxf(__uint_as_float(hdr[0]), QEPS) / F8MAX;
    float swv = fmaxf(__uint_as_float(hdr[1]), QEPS) / F8MAX;
    float s = sxv * swv;

    // C/D 32x32: col = lane&31, row = (reg&3) + 8*(reg>>2) + 4*(lane>>5)
    #pragma unroll
    for (int m = 0; m < 4; m++) {
        int row0 = bm * 256 + wr * 128 + m * 32 + 4 * hl;
        #pragma unroll
        for (int n = 0; n < 2; n++) {
            int col = bn * 256 + wc * 64 + n * 32 + l31;
            float bv = bias[col];
            #pragma unroll
            for (int reg = 0; reg < 16; reg++) {
                int row = row0 + (reg & 3) + 8 * (reg >> 2);
                C[(size_t)row * N + col] = acc[m][n][reg] * s + bv;
            }
        }
    }
#undef ISSUE
#undef RD8
#undef MMX
}

extern "C" void kernel_launch(void* const* d_in, const int* in_sizes, int n_in,
                              void* d_out, int out_size, void* d_ws, size_t ws_size,
                              hipStream_t stream)
{
    const float* x    = (const float*)d_in[0];
    const float* w    = (const float*)d_in[1];
    const float* bias = (const float*)d_in[2];
    float* out = (float*)d_out;

    int N = in_sizes[2];                 // 1024
    int K = in_sizes[1] / N;             // 1024
    int M = in_sizes[0] / K;             // 65536
    int nx = in_sizes[0];
    int nw = in_sizes[1];
    int nkt = K / 64;                    // 16

    uint8_t* ws = (uint8_t*)d_ws;
    unsigned* hdr = (unsigned*)ws;
    float* px = (float*)(ws + 64);
    float* pw = (float*)(ws + 64 + 4096);
    uint8_t* w8 = ws + 16384;
    uint8_t* x8 = ws + 16384 + (size_t)N * K;

    const int AX_BLOCKS = 1024;
    const int AW_BLOCKS = 256;

    amax_partial<<<AX_BLOCKS, 256, 0, stream>>>(x, nx / 4, px);
    amax_partial<<<AW_BLOCKS, 256, 0, stream>>>(w, nw / 4, pw);
    final_reduce<<<1, 256, 0, stream>>>(px, AX_BLOCKS, pw, AW_BLOCKS, hdr);

    quant_scramble<<<(M / 128) * nkt, 256, 0, stream>>>(x, x8, hdr, 0, nkt, K, 1);
    quant_scramble<<<(N / 128) * nkt, 256, 0, stream>>>(w, w8, hdr, 1, nkt, K, 0);

    int nbm = M / 256, nbn = N / 256;
    gemm_fp8_mx<<<nbm * nbn, 512, 0, stream>>>(x8, w8, out, bias, hdr, N, nkt, nbn);
}